// Round 2
// baseline (794.024 us; speedup 1.0000x reference)
//
#include <hip/hip_runtime.h>

// Problem constants (fixed by the reference): query (32,1,1024) f32, keys (32,4096,1024) f32
#define BATCH 32
#define S 4096
#define H 1024
#define H4 (H / 4)            // 256 float4 per row
#define NCHUNK 32             // S-chunks per batch -> grid = 32*32 = 1024 blocks (exactly 4/CU)
#define KPC (S / NCHUNK)      // 128 keys per chunk
#define BLOCK 256
#define NWAVE (BLOCK / 64)    // 4 waves
#define KPW (KPC / NWAVE)     // 32 keys per wave
#define DEPTH 4               // register-ring pipeline depth (rows in flight per wave)

// clang ext_vector_type: layout-identical to float4; __builtin_nontemporal_load accepts it.
typedef float vfloat4 __attribute__((ext_vector_type(4)));

static __device__ __forceinline__ vfloat4 nt_load(const vfloat4* p) {
  return __builtin_nontemporal_load(p);
}

// Pass 1: fused scores + online-softmax partial context. One read of keys total.
// Depth-4 register ring: rows i..i+3 resident/in-flight per wave (16 KB/wave vs 4 KB in r0).
// __launch_bounds__(256,4) pins VGPR<=128 so all 4 blocks/CU stay resident (16 waves/CU).
__global__ __launch_bounds__(BLOCK, 4) void attn_pass1(
    const float* __restrict__ query, const float* __restrict__ keys,
    float* __restrict__ scores,         // raw scores -> d_out weights region (normalized by pass 2)
    float* __restrict__ po,             // [BATCH][NCHUNK][H] partial context (unnormalized)
    float* __restrict__ pm,             // [BATCH][NCHUNK] partial max
    float* __restrict__ pl)             // [BATCH][NCHUNK] partial sum
{
  const int chunk = blockIdx.x;
  const int b     = blockIdx.y;
  const int lane  = threadIdx.x & 63;
  const int wave  = threadIdx.x >> 6;

  // Query fragment: 16 floats/lane, same layout as key fragments (reused -> normal load).
  const vfloat4* q4 = (const vfloat4*)(query + (size_t)b * H);
  const vfloat4 q0 = q4[lane], q1 = q4[lane + 64], q2 = q4[lane + 128], q3 = q4[lane + 192];

  const int s0 = chunk * KPC + wave * KPW;
  const vfloat4* base = (const vfloat4*)(keys + ((size_t)b * S + s0) * (size_t)H);

  // Prologue: fill the ring with rows 0..3 (16 loads, 16 KB in flight immediately).
  vfloat4 kreg[DEPTH][4];
  #pragma unroll
  for (int d = 0; d < DEPTH; ++d) {
    const vfloat4* p = base + (size_t)d * H4;
    kreg[d][0] = nt_load(p + lane);
    kreg[d][1] = nt_load(p + lane + 64);
    kreg[d][2] = nt_load(p + lane + 128);
    kreg[d][3] = nt_load(p + lane + 192);
  }

  float m = -3.0e38f, l = 0.0f;
  vfloat4 o0 = {0,0,0,0}, o1 = {0,0,0,0}, o2 = {0,0,0,0}, o3 = {0,0,0,0};

  // Unroll by DEPTH so slot index (i & 3) is compile-time -> kreg stays in registers.
  #pragma unroll 4
  for (int i = 0; i < KPW; ++i) {
    const int sl = i & (DEPTH - 1);

    // Four independent partial dot chains -> log-depth combine (serial chain ~20cy, not 64).
    float d0 = kreg[sl][0].x*q0.x + kreg[sl][0].y*q0.y + kreg[sl][0].z*q0.z + kreg[sl][0].w*q0.w;
    float d1 = kreg[sl][1].x*q1.x + kreg[sl][1].y*q1.y + kreg[sl][1].z*q1.z + kreg[sl][1].w*q1.w;
    float d2 = kreg[sl][2].x*q2.x + kreg[sl][2].y*q2.y + kreg[sl][2].z*q2.z + kreg[sl][2].w*q2.w;
    float d3 = kreg[sl][3].x*q3.x + kreg[sl][3].y*q3.y + kreg[sl][3].z*q3.z + kreg[sl][3].w*q3.w;
    float d  = (d0 + d1) + (d2 + d3);
    #pragma unroll
    for (int off = 1; off < 64; off <<= 1) d += __shfl_xor(d, off);  // all lanes get full dot

    if (lane == 0) scores[(size_t)b * S + (s0 + i)] = d;

    // Online softmax update; key row is in registers -> P*V costs no memory.
    const float mn = fmaxf(m, d);
    const float sc = __expf(m - mn);   // 0 on first iter (m = -3e38)
    const float p  = __expf(d - mn);
    l  = l * sc + p;
    o0 = o0*sc + p*kreg[sl][0];
    o1 = o1*sc + p*kreg[sl][1];
    o2 = o2*sc + p*kreg[sl][2];
    o3 = o3*sc + p*kreg[sl][3];
    m = mn;

    // Refill this slot with row i+DEPTH. Wave-uniform branch (s_cbranch, no exec mask):
    // tail iterations simply skip the load -- pipeline is draining there anyway, and we
    // avoid the 12.5% redundant-HBM-read a clamped pointer would cost under NT.
    if (i + DEPTH < KPW) {
      const vfloat4* p = base + (size_t)(i + DEPTH) * H4;
      kreg[sl][0] = nt_load(p + lane);
      kreg[sl][1] = nt_load(p + lane + 64);
      kreg[sl][2] = nt_load(p + lane + 128);
      kreg[sl][3] = nt_load(p + lane + 192);
    }
  }

  // Combine the 4 waves' (m, l, o) within the block via LDS.
  __shared__ float lds_o[NWAVE][H];     // 16 KiB
  __shared__ float lds_m[NWAVE], lds_l[NWAVE];
  vfloat4* lo = (vfloat4*)lds_o[wave];
  lo[lane] = o0; lo[lane + 64] = o1; lo[lane + 128] = o2; lo[lane + 192] = o3;
  if (lane == 0) { lds_m[wave] = m; lds_l[wave] = l; }
  __syncthreads();

  const int t = threadIdx.x;
  const float bm = fmaxf(fmaxf(lds_m[0], lds_m[1]), fmaxf(lds_m[2], lds_m[3]));
  float bl = 0.0f;
  vfloat4 acc = {0,0,0,0};
  #pragma unroll
  for (int w = 0; w < NWAVE; ++w) {
    const float scw = __expf(lds_m[w] - bm);
    bl += lds_l[w] * scw;
    const vfloat4 ow = ((const vfloat4*)lds_o[w])[t];
    acc += ow * scw;
  }
  ((vfloat4*)po)[((size_t)b * NCHUNK + chunk) * H4 + t] = acc;
  if (t == 0) { pm[b * NCHUNK + chunk] = bm; pl[b * NCHUNK + chunk] = bl; }
}

// Pass 2: merge the NCHUNK chunk partials per batch, emit context and normalized weights.
__global__ __launch_bounds__(256) void attn_pass2(
    const float* __restrict__ po, const float* __restrict__ pm, const float* __restrict__ pl,
    float* __restrict__ ctx, float* __restrict__ wts)
{
  const int b = blockIdx.x;
  const int t = threadIdx.x;
  __shared__ float s_scale[NCHUNK];
  __shared__ float s_m, s_invl;
  if (t == 0) {
    float m = -3.0e38f;
    for (int j = 0; j < NCHUNK; ++j) m = fmaxf(m, pm[b * NCHUNK + j]);
    float l = 0.0f;
    for (int j = 0; j < NCHUNK; ++j) {
      const float sc = __expf(pm[b * NCHUNK + j] - m);
      s_scale[j] = sc;
      l += pl[b * NCHUNK + j] * sc;
    }
    s_m = m; s_invl = 1.0f / l;
  }
  __syncthreads();
  const float m = s_m, invl = s_invl;

  vfloat4 acc = {0,0,0,0};
  for (int j = 0; j < NCHUNK; ++j) {
    const vfloat4 ow = ((const vfloat4*)po)[((size_t)b * NCHUNK + j) * H4 + t];
    acc += ow * s_scale[j];
  }
  acc *= invl;
  ((vfloat4*)ctx)[(size_t)b * H4 + t] = acc;

  // Normalize stored raw scores in place.
  for (int s = t; s < S; s += 256) {
    const float sc = wts[(size_t)b * S + s];
    wts[(size_t)b * S + s] = __expf(sc - m) * invl;
  }
}

extern "C" void kernel_launch(void* const* d_in, const int* in_sizes, int n_in,
                              void* d_out, int out_size, void* d_ws, size_t ws_size,
                              hipStream_t stream) {
  const float* query = (const float*)d_in[0];   // 32*1*1024
  const float* keys  = (const float*)d_in[1];   // 32*4096*1024

  float* ctx = (float*)d_out;                   // context: first 32*1024 floats
  float* wts = (float*)d_out + BATCH * H;       // weights: next 32*4096 floats

  float* po = (float*)d_ws;                     // 32*32*1024 floats = 4 MiB
  float* pm = po + (size_t)BATCH * NCHUNK * H;  // 1024 floats
  float* pl = pm + BATCH * NCHUNK;              // 1024 floats

  attn_pass1<<<dim3(NCHUNK, BATCH), BLOCK, 0, stream>>>(query, keys, wts, po, pm, pl);
  attn_pass2<<<BATCH, 256, 0, stream>>>(po, pm, pl, ctx, wts);
}

// Round 3
// 684.284 us; speedup vs baseline: 1.1604x; 1.1604x over previous
//
#include <hip/hip_runtime.h>
#include <stdint.h>

// Problem constants (fixed by the reference): query (32,1,1024) f32, keys (32,4096,1024) f32
#define BATCH 32
#define S 4096
#define H 1024
#define H4 (H / 4)            // 256 float4 per row
#define NCHUNK 16             // grid = 16*32 = 512 blocks -> exactly 2 blocks/CU
#define KPC (S / NCHUNK)      // 256 keys per block
#define BLOCK 256
#define NWAVE (BLOCK / 64)    // 4 waves
#define TROWS 8               // rows per LDS tile (32 KB)
#define NTILES (KPC / TROWS)  // 32 tiles per block
#define RPW (TROWS / NWAVE)   // 2 rows per wave per tile

// clang ext_vector_type: layout-identical to float4, full vector arithmetic.
typedef float vfloat4 __attribute__((ext_vector_type(4)));

// Pass 1: fused scores + online-softmax partial context. One read of keys total.
// Pipeline depth now lives in LDS via global_load_lds (zero VGPR cost): per tile,
// STAGE(t+1) is issued before COMPUTE(t), so 32 KB/block stays in flight during
// compute and the pre-barrier vmcnt(0) drain only pays residual transfer time.
__global__ __launch_bounds__(BLOCK) void attn_pass1(
    const float* __restrict__ query, const float* __restrict__ keys,
    float* __restrict__ scores,         // raw scores -> d_out weights region (normalized by pass 2)
    float* __restrict__ po,             // [BATCH][NCHUNK][H] partial context (unnormalized)
    float* __restrict__ pm,             // [BATCH][NCHUNK] partial max
    float* __restrict__ pl)             // [BATCH][NCHUNK] partial sum
{
  const int chunk = blockIdx.x;
  const int b     = blockIdx.y;
  const int lane  = threadIdx.x & 63;
  const int wave  = threadIdx.x >> 6;

  __shared__ __align__(16) float buf[2][TROWS][H];   // 64 KB double-buffered key tile
  __shared__ float lds_m[NWAVE], lds_l[NWAVE];

  // Query fragment: 16 floats/lane, same layout as key fragments.
  const vfloat4* q4 = (const vfloat4*)(query + (size_t)b * H);
  const vfloat4 q0 = q4[lane], q1 = q4[lane + 64], q2 = q4[lane + 128], q3 = q4[lane + 192];

  const float* kb = keys + ((size_t)b * S + (size_t)chunk * KPC) * (size_t)H;

  // Each wave stages exactly the rows it will consume. global_load_lds: per-lane
  // global source (g + lane*16B), wave-uniform LDS base (HW adds lane*16B).
  auto stage = [&](int t, int pb) {
    #pragma unroll
    for (int r = 0; r < RPW; ++r) {
      const int row = wave * RPW + r;
      const float* g = kb + (size_t)(t * TROWS + row) * H + lane * 4;
      #pragma unroll
      for (int qo = 0; qo < 4; ++qo) {   // 4 x 1 KB segments per 4 KB row
        __builtin_amdgcn_global_load_lds(
            (const __attribute__((address_space(1))) uint32_t*)(g + qo * 256),
            (__attribute__((address_space(3))) uint32_t*)(&buf[pb][row][qo * 256]),
            16, 0, 0);
      }
    }
  };

  float m = -3.0e38f, l = 0.0f;
  vfloat4 o0 = {0,0,0,0}, o1 = {0,0,0,0}, o2 = {0,0,0,0}, o3 = {0,0,0,0};

  stage(0, 0);
  __syncthreads();                       // vmcnt(0) drain: tile 0 resident

  int pb = 0;
  for (int t = 0; t < NTILES; ++t) {
    if (t + 1 < NTILES) stage(t + 1, pb ^ 1);   // issue BEFORE compute -> overlap

    #pragma unroll
    for (int r = 0; r < RPW; ++r) {
      const int row = wave * RPW + r;
      const vfloat4* lrow = (const vfloat4*)&buf[pb][row][0];
      const vfloat4 k0 = lrow[lane],       k1 = lrow[lane + 64],
                    k2 = lrow[lane + 128], k3 = lrow[lane + 192];   // ds_read_b128 x4

      float d0 = k0.x*q0.x + k0.y*q0.y + k0.z*q0.z + k0.w*q0.w;
      float d1 = k1.x*q1.x + k1.y*q1.y + k1.z*q1.z + k1.w*q1.w;
      float d2 = k2.x*q2.x + k2.y*q2.y + k2.z*q2.z + k2.w*q2.w;
      float d3 = k3.x*q3.x + k3.y*q3.y + k3.z*q3.z + k3.w*q3.w;
      float d  = (d0 + d1) + (d2 + d3);
      #pragma unroll
      for (int off = 1; off < 64; off <<= 1) d += __shfl_xor(d, off);

      if (lane == 0) scores[(size_t)b * S + chunk * KPC + t * TROWS + row] = d;

      // Online softmax update; key row is in registers -> P*V costs no memory.
      const float mn = fmaxf(m, d);
      const float sc = __expf(m - mn);   // 0 on first iter (m = -3e38)
      const float p  = __expf(d - mn);
      l  = l * sc + p;
      o0 = o0*sc + p*k0;
      o1 = o1*sc + p*k1;
      o2 = o2*sc + p*k2;
      o3 = o3*sc + p*k3;
      m = mn;
    }

    __syncthreads();   // tile t+1 arrived (vmcnt drain); buffer pb free for reuse
    pb ^= 1;
  }

  // Combine the 4 waves' (m, l, o) within the block; reuse buf[0] (16 KB needed).
  float* red = &buf[0][0][0];
  vfloat4* lo = (vfloat4*)(red + wave * H);
  lo[lane] = o0; lo[lane + 64] = o1; lo[lane + 128] = o2; lo[lane + 192] = o3;
  if (lane == 0) { lds_m[wave] = m; lds_l[wave] = l; }
  __syncthreads();

  const int tid = threadIdx.x;
  const float bm = fmaxf(fmaxf(lds_m[0], lds_m[1]), fmaxf(lds_m[2], lds_m[3]));
  float bl = 0.0f;
  vfloat4 acc = {0,0,0,0};
  #pragma unroll
  for (int w = 0; w < NWAVE; ++w) {
    const float scw = __expf(lds_m[w] - bm);
    bl += lds_l[w] * scw;
    const vfloat4 ow = ((const vfloat4*)(red + w * H))[tid];
    acc += ow * scw;
  }
  ((vfloat4*)po)[((size_t)b * NCHUNK + chunk) * H4 + tid] = acc;
  if (tid == 0) { pm[b * NCHUNK + chunk] = bm; pl[b * NCHUNK + chunk] = bl; }
}

// Pass 2: merge the NCHUNK chunk partials per batch, emit context and normalized weights.
__global__ __launch_bounds__(256) void attn_pass2(
    const float* __restrict__ po, const float* __restrict__ pm, const float* __restrict__ pl,
    float* __restrict__ ctx, float* __restrict__ wts)
{
  const int b = blockIdx.x;
  const int t = threadIdx.x;
  __shared__ float s_scale[NCHUNK];
  __shared__ float s_m, s_invl;
  if (t == 0) {
    float m = -3.0e38f;
    for (int j = 0; j < NCHUNK; ++j) m = fmaxf(m, pm[b * NCHUNK + j]);
    float l = 0.0f;
    for (int j = 0; j < NCHUNK; ++j) {
      const float sc = __expf(pm[b * NCHUNK + j] - m);
      s_scale[j] = sc;
      l += pl[b * NCHUNK + j] * sc;
    }
    s_m = m; s_invl = 1.0f / l;
  }
  __syncthreads();
  const float m = s_m, invl = s_invl;

  vfloat4 acc = {0,0,0,0};
  for (int j = 0; j < NCHUNK; ++j) {
    const vfloat4 ow = ((const vfloat4*)po)[((size_t)b * NCHUNK + j) * H4 + t];
    acc += ow * s_scale[j];
  }
  acc *= invl;
  ((vfloat4*)ctx)[(size_t)b * H4 + t] = acc;

  // Normalize stored raw scores in place.
  for (int s = t; s < S; s += 256) {
    const float sc = wts[(size_t)b * S + s];
    wts[(size_t)b * S + s] = __expf(sc - m) * invl;
  }
}

extern "C" void kernel_launch(void* const* d_in, const int* in_sizes, int n_in,
                              void* d_out, int out_size, void* d_ws, size_t ws_size,
                              hipStream_t stream) {
  const float* query = (const float*)d_in[0];   // 32*1*1024
  const float* keys  = (const float*)d_in[1];   // 32*4096*1024

  float* ctx = (float*)d_out;                   // context: first 32*1024 floats
  float* wts = (float*)d_out + BATCH * H;       // weights: next 32*4096 floats

  float* po = (float*)d_ws;                     // 32*16*1024 floats = 2 MiB
  float* pm = po + (size_t)BATCH * NCHUNK * H;  // 512 floats
  float* pl = pm + BATCH * NCHUNK;              // 512 floats

  attn_pass1<<<dim3(NCHUNK, BATCH), BLOCK, 0, stream>>>(query, keys, wts, po, pm, pl);
  attn_pass2<<<BATCH, 256, 0, stream>>>(po, pm, pl, ctx, wts);
}

// Round 4
// 683.353 us; speedup vs baseline: 1.1620x; 1.0014x over previous
//
#include <hip/hip_runtime.h>
#include <stdint.h>

// Problem constants (fixed by the reference): query (32,1,1024) f32, keys (32,4096,1024) f32
#define BATCH 32
#define S 4096
#define H 1024
#define H4 (H / 4)            // 256 float4 per row
#define NCHUNK 16             // grid = 16*32 = 512 blocks -> exactly 2 blocks/CU (LDS-capped)
#define KPC (S / NCHUNK)      // 256 keys per block
#define BLOCK 256
#define NWAVE (BLOCK / 64)    // 4 waves
#define KPW (KPC / NWAVE)     // 64 keys per wave (== 64 lanes: one score per lane)
#define NSLOT 4               // per-wave LDS ring depth: 3 rows in flight, 1 being consumed

// clang ext_vector_type: layout-identical to float4, full vector arithmetic.
typedef float vfloat4 __attribute__((ext_vector_type(4)));

// Counted vmcnt wait (T4): never drain to 0 in the main loop. "memory" clobber pins
// global_load_lds / ds_read on either side; sched_barrier(0) stops hoisting (rule #18).
#define WAITV(N) do { asm volatile("s_waitcnt vmcnt(" #N ")" ::: "memory"); \
                      __builtin_amdgcn_sched_barrier(0); } while (0)

// Pass 1: fused scores + online-softmax partial context. One read of keys total.
// Per-wave private LDS ring staged with global_load_lds: each wave writes AND reads only
// its own slots, so the main loop has NO barriers and NO vmcnt(0) drain — 3 rows (12 KB)
// per wave stay in flight at all times (~96-128 KB/CU vs ~64 KB in all prior variants).
__global__ __launch_bounds__(BLOCK) void attn_pass1(
    const float* __restrict__ query, const float* __restrict__ keys,
    float* __restrict__ scores,         // raw scores -> d_out weights region (normalized by pass 2)
    float* __restrict__ po,             // [BATCH][NCHUNK][H] partial context (unnormalized)
    float* __restrict__ pm,             // [BATCH][NCHUNK] partial max
    float* __restrict__ pl)             // [BATCH][NCHUNK] partial sum
{
  const int chunk = blockIdx.x;
  const int b     = blockIdx.y;
  const int lane  = threadIdx.x & 63;
  const int wave  = threadIdx.x >> 6;

  __shared__ __align__(16) float ring[NWAVE][NSLOT][H];   // 64 KB: 4 KB/slot, 4 slots/wave
  __shared__ float lds_m[NWAVE], lds_l[NWAVE];

  // Query fragment first (its 4 loads are oldest in the vmcnt FIFO, retired by the
  // first counted wait). 16 floats/lane, same layout as key fragments.
  const vfloat4* q4 = (const vfloat4*)(query + (size_t)b * H);
  const vfloat4 q0 = q4[lane], q1 = q4[lane + 64], q2 = q4[lane + 128], q3 = q4[lane + 192];

  // This wave's private 64-row strip of keys.
  const float* wbase = keys + ((size_t)b * S + (size_t)chunk * KPC + (size_t)wave * KPW) * (size_t)H;

  // Stage one 4 KB key row into this wave's LDS slot: per-lane global source,
  // wave-uniform LDS base (HW adds lane*16B). 4 vmcnt increments per row.
  auto stage = [&](int r, int sl) {
    const float* g = wbase + (size_t)r * H + lane * 4;
    #pragma unroll
    for (int qo = 0; qo < 4; ++qo) {
      __builtin_amdgcn_global_load_lds(
          (const __attribute__((address_space(1))) uint32_t*)(g + qo * 256),
          (__attribute__((address_space(3))) uint32_t*)(&ring[wave][sl][qo * 256]),
          16, 0, 0);
    }
  };

  // Prologue: 3 rows in flight. sched_barrier keeps issue order = FIFO count order.
  stage(0, 0); __builtin_amdgcn_sched_barrier(0);
  stage(1, 1); __builtin_amdgcn_sched_barrier(0);
  stage(2, 2); __builtin_amdgcn_sched_barrier(0);

  float m = -3.0e38f, l = 0.0f, sreg = 0.0f;
  vfloat4 o0 = {0,0,0,0}, o1 = {0,0,0,0}, o2 = {0,0,0,0}, o3 = {0,0,0,0};

  auto body = [&](int i) {
    const vfloat4* lrow = (const vfloat4*)&ring[wave][i & (NSLOT - 1)][0];
    const vfloat4 k0 = lrow[lane],       k1 = lrow[lane + 64],
                  k2 = lrow[lane + 128], k3 = lrow[lane + 192];   // ds_read_b128 x4

    float d0 = k0.x*q0.x + k0.y*q0.y + k0.z*q0.z + k0.w*q0.w;
    float d1 = k1.x*q1.x + k1.y*q1.y + k1.z*q1.z + k1.w*q1.w;
    float d2 = k2.x*q2.x + k2.y*q2.y + k2.z*q2.z + k2.w*q2.w;
    float d3 = k3.x*q3.x + k3.y*q3.y + k3.z*q3.z + k3.w*q3.w;
    float d  = (d0 + d1) + (d2 + d3);
    #pragma unroll
    for (int off = 1; off < 64; off <<= 1) d += __shfl_xor(d, off);  // all lanes get full dot

    sreg = (lane == i) ? d : sreg;   // lane i latches row i's score; one store at the end

    // Online softmax update; key row is in registers -> P*V costs no memory.
    const float mn = fmaxf(m, d);
    const float sc = __expf(m - mn);   // 0 on first iter (m = -3e38)
    const float p  = __expf(d - mn);
    l  = l * sc + p;
    o0 = o0*sc + p*k0;
    o1 = o1*sc + p*k1;
    o2 = o2*sc + p*k2;
    o3 = o3*sc + p*k3;
    m = mn;
  };

  // Steady state: stage row i+3, wait to 12 outstanding (rows i+1..i+3 in flight,
  // row i complete), consume row i. vmcnt count is exact: no other VM ops in the loop.
  #pragma unroll 2
  for (int i = 0; i < KPW - 3; ++i) {
    stage(i + 3, (i + 3) & (NSLOT - 1));
    WAITV(12);
    body(i);
  }
  // Epilogue drain: 12 -> 8 -> 4 -> 0, never stalling more than one row early.
  WAITV(8);  body(KPW - 3);
  WAITV(4);  body(KPW - 2);
  WAITV(0);  body(KPW - 1);

  // One coalesced 256 B score store per wave (replaces 64 divergent lane-0 stores).
  scores[(size_t)b * S + (size_t)chunk * KPC + (size_t)wave * KPW + lane] = sreg;

  // Combine the 4 waves' (m, l, o) within the block; reuse ring LDS (all loads retired
  // by each wave's WAITV(0), and the barrier orders every wave past its loop).
  __syncthreads();
  float* red = &ring[0][0][0];
  vfloat4* lo = (vfloat4*)(red + wave * H);
  lo[lane] = o0; lo[lane + 64] = o1; lo[lane + 128] = o2; lo[lane + 192] = o3;
  if (lane == 0) { lds_m[wave] = m; lds_l[wave] = l; }
  __syncthreads();

  const int tid = threadIdx.x;
  const float bm = fmaxf(fmaxf(lds_m[0], lds_m[1]), fmaxf(lds_m[2], lds_m[3]));
  float bl = 0.0f;
  vfloat4 acc = {0,0,0,0};
  #pragma unroll
  for (int w = 0; w < NWAVE; ++w) {
    const float scw = __expf(lds_m[w] - bm);
    bl += lds_l[w] * scw;
    const vfloat4 ow = ((const vfloat4*)(red + w * H))[tid];
    acc += ow * scw;
  }
  ((vfloat4*)po)[((size_t)b * NCHUNK + chunk) * H4 + tid] = acc;
  if (tid == 0) { pm[b * NCHUNK + chunk] = bm; pl[b * NCHUNK + chunk] = bl; }
}

// Pass 2: merge the NCHUNK chunk partials per batch, emit context and normalized weights.
__global__ __launch_bounds__(256) void attn_pass2(
    const float* __restrict__ po, const float* __restrict__ pm, const float* __restrict__ pl,
    float* __restrict__ ctx, float* __restrict__ wts)
{
  const int b = blockIdx.x;
  const int t = threadIdx.x;
  __shared__ float s_scale[NCHUNK];
  __shared__ float s_m, s_invl;
  if (t == 0) {
    float m = -3.0e38f;
    for (int j = 0; j < NCHUNK; ++j) m = fmaxf(m, pm[b * NCHUNK + j]);
    float l = 0.0f;
    for (int j = 0; j < NCHUNK; ++j) {
      const float sc = __expf(pm[b * NCHUNK + j] - m);
      s_scale[j] = sc;
      l += pl[b * NCHUNK + j] * sc;
    }
    s_m = m; s_invl = 1.0f / l;
  }
  __syncthreads();
  const float m = s_m, invl = s_invl;

  vfloat4 acc = {0,0,0,0};
  for (int j = 0; j < NCHUNK; ++j) {
    const vfloat4 ow = ((const vfloat4*)po)[((size_t)b * NCHUNK + j) * H4 + t];
    acc += ow * s_scale[j];
  }
  acc *= invl;
  ((vfloat4*)ctx)[(size_t)b * H4 + t] = acc;

  // Normalize stored raw scores in place (vectorized: 4096 floats = 1024 float4).
  vfloat4* w4 = (vfloat4*)(wts + (size_t)b * S);
  for (int s = t; s < S / 4; s += 256) {
    vfloat4 v = w4[s];
    v.x = __expf(v.x - m) * invl;
    v.y = __expf(v.y - m) * invl;
    v.z = __expf(v.z - m) * invl;
    v.w = __expf(v.w - m) * invl;
    w4[s] = v;
  }
}

extern "C" void kernel_launch(void* const* d_in, const int* in_sizes, int n_in,
                              void* d_out, int out_size, void* d_ws, size_t ws_size,
                              hipStream_t stream) {
  const float* query = (const float*)d_in[0];   // 32*1*1024
  const float* keys  = (const float*)d_in[1];   // 32*4096*1024

  float* ctx = (float*)d_out;                   // context: first 32*1024 floats
  float* wts = (float*)d_out + BATCH * H;       // weights: next 32*4096 floats

  float* po = (float*)d_ws;                     // 32*16*1024 floats = 2 MiB
  float* pm = po + (size_t)BATCH * NCHUNK * H;  // 512 floats
  float* pl = pm + BATCH * NCHUNK;              // 512 floats

  attn_pass1<<<dim3(NCHUNK, BATCH), BLOCK, 0, stream>>>(query, keys, wts, po, pm, pl);
  attn_pass2<<<BATCH, 256, 0, stream>>>(po, pm, pl, ctx, wts);
}

// Round 5
// 661.570 us; speedup vs baseline: 1.2002x; 1.0329x over previous
//
#include <hip/hip_runtime.h>

// Problem constants (fixed by the reference): query (32,1,1024) f32, keys (32,4096,1024) f32
#define BATCH 32
#define S 4096
#define H 1024
#define H4 (H / 4)            // 256 float4 per row
#define NCHUNK 32             // S-chunks per batch -> grid = 32*32 = 1024 blocks (4/CU, 4 waves/SIMD)
#define KPC (S / NCHUNK)      // 128 keys per chunk
#define BLOCK 256
#define NWAVE (BLOCK / 64)    // 4 waves
#define KPW (KPC / NWAVE)     // 32 keys per wave

// Native vector type: __builtin_nontemporal_load rejects HIP_vector_type (struct),
// but accepts clang ext_vector_type. Layout-identical to float4.
typedef float vfloat4 __attribute__((ext_vector_type(4)));

static __device__ __forceinline__ vfloat4 nt_load(const vfloat4* p) {
  return __builtin_nontemporal_load(p);
}

// Pass 1: fused scores + online-softmax partial context. One read of keys total.
// Structure identical to the proven-best r0 kernel (NT loads, depth-1 register
// prefetch with clamped tail pointer, 16 waves/CU). Micro-deltas only:
//   - dot product as 4 independent chains + log-depth combine (shorter serial path)
//   - scores latched per-lane, one coalesced 128B store per wave after the loop
__global__ __launch_bounds__(BLOCK) void attn_pass1(
    const float* __restrict__ query, const float* __restrict__ keys,
    float* __restrict__ scores,         // raw scores -> d_out weights region (normalized by pass 2)
    float* __restrict__ po,             // [BATCH][NCHUNK][H] partial context (unnormalized)
    float* __restrict__ pm,             // [BATCH][NCHUNK] partial max
    float* __restrict__ pl)             // [BATCH][NCHUNK] partial sum
{
  const int chunk = blockIdx.x;
  const int b     = blockIdx.y;
  const int lane  = threadIdx.x & 63;
  const int wave  = threadIdx.x >> 6;

  // Query fragment: 16 floats/lane, same layout as key fragments (reused -> normal load).
  const vfloat4* q4 = (const vfloat4*)(query + (size_t)b * H);
  const vfloat4 q0 = q4[lane], q1 = q4[lane + 64], q2 = q4[lane + 128], q3 = q4[lane + 192];

  const int s0 = chunk * KPC + wave * KPW;
  const vfloat4* kp = (const vfloat4*)(keys + ((size_t)b * S + s0) * (size_t)H);

  // Preload first key row (1-deep prefetch pipeline; streaming -> nontemporal).
  vfloat4 k0 = nt_load(kp + lane), k1 = nt_load(kp + lane + 64),
          k2 = nt_load(kp + lane + 128), k3 = nt_load(kp + lane + 192);

  float m = -3.0e38f, l = 0.0f, sreg = 0.0f;
  vfloat4 o0 = {0,0,0,0}, o1 = {0,0,0,0}, o2 = {0,0,0,0}, o3 = {0,0,0,0};

  for (int i = 0; i < KPW; ++i) {
    // Unconditional prefetch with clamped pointer: last iteration re-reads the
    // current row (L2-hit) instead of branching — keeps loads hoisted and
    // exec-mask-free so vmcnt can retire behind the compute chain.
    const vfloat4* kn = (i + 1 < KPW) ? (kp + H4) : kp;
    const vfloat4 n0 = nt_load(kn + lane),       n1 = nt_load(kn + lane + 64),
                  n2 = nt_load(kn + lane + 128), n3 = nt_load(kn + lane + 192);

    // Four independent partial chains -> log-depth combine (serial chain ~20cy, not 64).
    float d0 = k0.x*q0.x + k0.y*q0.y + k0.z*q0.z + k0.w*q0.w;
    float d1 = k1.x*q1.x + k1.y*q1.y + k1.z*q1.z + k1.w*q1.w;
    float d2 = k2.x*q2.x + k2.y*q2.y + k2.z*q2.z + k2.w*q2.w;
    float d3 = k3.x*q3.x + k3.y*q3.y + k3.z*q3.z + k3.w*q3.w;
    float d  = (d0 + d1) + (d2 + d3);
    #pragma unroll
    for (int off = 1; off < 64; off <<= 1) d += __shfl_xor(d, off);  // all lanes get full dot

    sreg = (lane == i) ? d : sreg;   // lane i latches row i's score (KPW == 32 <= 64 lanes)

    // Online softmax update; key row is already in registers -> P*V costs no memory.
    const float mn = fmaxf(m, d);
    const float sc = __expf(m - mn);   // 0 on first iter (m = -3e38)
    const float p  = __expf(d - mn);
    l = l * sc + p;
    o0 = o0*sc + p*k0;
    o1 = o1*sc + p*k1;
    o2 = o2*sc + p*k2;
    o3 = o3*sc + p*k3;
    m = mn;
    k0 = n0; k1 = n1; k2 = n2; k3 = n3;
    kp = kn;
  }

  // One coalesced 128B score store per wave (lanes 0..KPW-1 hold rows 0..KPW-1).
  if (lane < KPW) scores[(size_t)b * S + s0 + lane] = sreg;

  // Combine the 4 waves' (m, l, o) within the block via LDS.
  __shared__ float lds_o[NWAVE][H];     // 16 KiB
  __shared__ float lds_m[NWAVE], lds_l[NWAVE];
  vfloat4* lo = (vfloat4*)lds_o[wave];
  lo[lane] = o0; lo[lane + 64] = o1; lo[lane + 128] = o2; lo[lane + 192] = o3;
  if (lane == 0) { lds_m[wave] = m; lds_l[wave] = l; }
  __syncthreads();

  const int t = threadIdx.x;
  const float bm = fmaxf(fmaxf(lds_m[0], lds_m[1]), fmaxf(lds_m[2], lds_m[3]));
  float bl = 0.0f;
  vfloat4 acc = {0,0,0,0};
  #pragma unroll
  for (int w = 0; w < NWAVE; ++w) {
    const float scw = __expf(lds_m[w] - bm);
    bl += lds_l[w] * scw;
    const vfloat4 ow = ((const vfloat4*)lds_o[w])[t];
    acc += ow * scw;
  }
  ((vfloat4*)po)[((size_t)b * NCHUNK + chunk) * H4 + t] = acc;
  if (t == 0) { pm[b * NCHUNK + chunk] = bm; pl[b * NCHUNK + chunk] = bl; }
}

// Pass 2: merge the NCHUNK chunk partials per batch, emit context and normalized weights.
__global__ __launch_bounds__(256) void attn_pass2(
    const float* __restrict__ po, const float* __restrict__ pm, const float* __restrict__ pl,
    float* __restrict__ ctx, float* __restrict__ wts)
{
  const int b = blockIdx.x;
  const int t = threadIdx.x;
  __shared__ float s_scale[NCHUNK];
  __shared__ float s_m, s_invl;
  if (t == 0) {
    float m = -3.0e38f;
    for (int j = 0; j < NCHUNK; ++j) m = fmaxf(m, pm[b * NCHUNK + j]);
    float l = 0.0f;
    for (int j = 0; j < NCHUNK; ++j) {
      const float sc = __expf(pm[b * NCHUNK + j] - m);
      s_scale[j] = sc;
      l += pl[b * NCHUNK + j] * sc;
    }
    s_m = m; s_invl = 1.0f / l;
  }
  __syncthreads();
  const float m = s_m, invl = s_invl;

  vfloat4 acc = {0,0,0,0};
  for (int j = 0; j < NCHUNK; ++j) {
    const vfloat4 ow = ((const vfloat4*)po)[((size_t)b * NCHUNK + j) * H4 + t];
    acc += ow * s_scale[j];
  }
  acc *= invl;
  ((vfloat4*)ctx)[(size_t)b * H4 + t] = acc;

  // Normalize stored raw scores in place (vectorized: 4096 floats = 1024 float4).
  vfloat4* w4 = (vfloat4*)(wts + (size_t)b * S);
  for (int s = t; s < S / 4; s += 256) {
    vfloat4 v = w4[s];
    v.x = __expf(v.x - m) * invl;
    v.y = __expf(v.y - m) * invl;
    v.z = __expf(v.z - m) * invl;
    v.w = __expf(v.w - m) * invl;
    w4[s] = v;
  }
}

extern "C" void kernel_launch(void* const* d_in, const int* in_sizes, int n_in,
                              void* d_out, int out_size, void* d_ws, size_t ws_size,
                              hipStream_t stream) {
  const float* query = (const float*)d_in[0];   // 32*1*1024
  const float* keys  = (const float*)d_in[1];   // 32*4096*1024

  float* ctx = (float*)d_out;                   // context: first 32*1024 floats
  float* wts = (float*)d_out + BATCH * H;       // weights: next 32*4096 floats

  float* po = (float*)d_ws;                     // 32*32*1024 floats = 4 MiB
  float* pm = po + (size_t)BATCH * NCHUNK * H;  // 1024 floats
  float* pl = pm + BATCH * NCHUNK;              // 1024 floats

  attn_pass1<<<dim3(NCHUNK, BATCH), BLOCK, 0, stream>>>(query, keys, wts, po, pm, pl);
  attn_pass2<<<BATCH, 256, 0, stream>>>(po, pm, pl, ctx, wts);
}